// Round 1
// baseline (203.477 us; speedup 1.0000x reference)
//
#include <hip/hip_runtime.h>

typedef short bf16x8 __attribute__((ext_vector_type(8)));
typedef float f32x4 __attribute__((ext_vector_type(4)));

#define SWZ(r, cb) ((((int)(r)) << 7) + (((int)(cb)) ^ ((((int)(r)) & 7) << 4)))

__device__ __forceinline__ unsigned short f2b(float f) {
    unsigned u = __builtin_bit_cast(unsigned, f);
    u = (u + 0x7FFFu + ((u >> 16) & 1u)) >> 16;
    return (unsigned short)u;
}
__device__ __forceinline__ float b2f(unsigned short h) {
    unsigned u = ((unsigned)h) << 16;
    return __builtin_bit_cast(float, u);
}

// ---------------- LayerNorm: one wave per token, H=768 ----------------
__global__ __launch_bounds__(256) void ln_kernel(const float* __restrict__ x,
                                                 const float* __restrict__ gamma,
                                                 const float* __restrict__ beta,
                                                 unsigned short* __restrict__ h) {
    int lane = threadIdx.x & 63, wv = threadIdx.x >> 6;
    int tok = blockIdx.x * 4 + wv;
    const float* xr = x + (size_t)tok * 768;
    float v[12];
#pragma unroll
    for (int c = 0; c < 3; c++) {
        float4 t = *(const float4*)(xr + c * 256 + lane * 4);
        v[c * 4 + 0] = t.x; v[c * 4 + 1] = t.y; v[c * 4 + 2] = t.z; v[c * 4 + 3] = t.w;
    }
    float s = 0.f;
#pragma unroll
    for (int j = 0; j < 12; j++) s += v[j];
#pragma unroll
    for (int m = 1; m < 64; m <<= 1) s += __shfl_xor(s, m, 64);
    float mu = s * (1.0f / 768.0f);
    float s2 = 0.f;
#pragma unroll
    for (int j = 0; j < 12; j++) { float d = v[j] - mu; s2 += d * d; }
#pragma unroll
    for (int m = 1; m < 64; m <<= 1) s2 += __shfl_xor(s2, m, 64);
    float rstd = 1.0f / sqrtf(s2 * (1.0f / 768.0f) + 1e-12f);
    unsigned short* hr = h + (size_t)tok * 768;
#pragma unroll
    for (int c = 0; c < 3; c++) {
        float4 g = *(const float4*)(gamma + c * 256 + lane * 4);
        float4 bt = *(const float4*)(beta + c * 256 + lane * 4);
        ushort4 o;
        o.x = f2b((v[c * 4 + 0] - mu) * rstd * g.x + bt.x);
        o.y = f2b((v[c * 4 + 1] - mu) * rstd * g.y + bt.y);
        o.z = f2b((v[c * 4 + 2] - mu) * rstd * g.z + bt.z);
        o.w = f2b((v[c * 4 + 3] - mu) * rstd * g.w + bt.w);
        *(ushort4*)(hr + c * 256 + lane * 4) = o;
    }
}

// ---------------- QKV GEMM: M=4096, N=1280 (768|256|256), K=768 ----------------
__global__ __launch_bounds__(256) void gemm_qkv(const unsigned short* __restrict__ A,
                                                const float* __restrict__ Wq,
                                                const float* __restrict__ Wk,
                                                const float* __restrict__ Wv,
                                                const float* __restrict__ bq,
                                                const float* __restrict__ bk,
                                                const float* __restrict__ bv,
                                                unsigned short* __restrict__ qo,
                                                unsigned short* __restrict__ ko,
                                                unsigned short* __restrict__ vo) {
    __shared__ short As[128 * 64];
    __shared__ short Bs[128 * 64];
    const int m0 = blockIdx.x * 128;
    const int n0 = blockIdx.y * 128;
    const float* W; const float* bias; unsigned short* dst; int ldw, c0, ldd;
    if (n0 < 768)       { W = Wq; bias = bq; dst = qo; ldw = 768; c0 = n0;        ldd = 768; }
    else if (n0 < 1024) { W = Wk; bias = bk; dst = ko; ldw = 256; c0 = n0 - 768;  ldd = 256; }
    else                { W = Wv; bias = bv; dst = vo; ldw = 256; c0 = n0 - 1024; ldd = 256; }
    const int tid = threadIdx.x, lane = tid & 63, w = tid >> 6;
    const int wr = w >> 1, wc = w & 1;
    f32x4 acc[4][4];
#pragma unroll
    for (int m = 0; m < 4; m++)
#pragma unroll
        for (int n = 0; n < 4; n++) acc[m][n] = (f32x4){0.f, 0.f, 0.f, 0.f};

    for (int k0 = 0; k0 < 768; k0 += 64) {
        // stage A tile (128 x 64 bf16), swizzled
#pragma unroll
        for (int it = 0; it < 4; it++) {
            int idx = tid + it * 256;
            int r = idx >> 3, ch = idx & 7;
            bf16x8 val = *(const bf16x8*)(A + (size_t)(m0 + r) * 768 + k0 + ch * 8);
            *(bf16x8*)((char*)As + SWZ(r, ch * 16)) = val;
        }
        // stage B tile transposed: Bs[n][k] = bf16(W[k0+k][c0+n]), swizzled
        {
            int kk = tid >> 2, cg = (tid & 3) * 32;
            const float* src = W + (size_t)(k0 + kk) * ldw + c0 + cg;
#pragma unroll
            for (int jj = 0; jj < 8; jj++) {
                float4 f = *(const float4*)(src + jj * 4);
                int n = cg + jj * 4;
                *(short*)((char*)Bs + SWZ(n + 0, kk * 2)) = (short)f2b(f.x);
                *(short*)((char*)Bs + SWZ(n + 1, kk * 2)) = (short)f2b(f.y);
                *(short*)((char*)Bs + SWZ(n + 2, kk * 2)) = (short)f2b(f.z);
                *(short*)((char*)Bs + SWZ(n + 3, kk * 2)) = (short)f2b(f.w);
            }
        }
        __syncthreads();
#pragma unroll
        for (int ks = 0; ks < 2; ks++) {
            bf16x8 a[4], b[4];
#pragma unroll
            for (int m = 0; m < 4; m++)
                a[m] = *(const bf16x8*)((char*)As + SWZ(wr * 64 + m * 16 + (lane & 15), (lane >> 4) * 16 + ks * 64));
#pragma unroll
            for (int n = 0; n < 4; n++)
                b[n] = *(const bf16x8*)((char*)Bs + SWZ(wc * 64 + n * 16 + (lane & 15), (lane >> 4) * 16 + ks * 64));
#pragma unroll
            for (int m = 0; m < 4; m++)
#pragma unroll
                for (int n = 0; n < 4; n++)
                    acc[m][n] = __builtin_amdgcn_mfma_f32_16x16x32_bf16(a[m], b[n], acc[m][n], 0, 0, 0);
        }
        __syncthreads();
    }
#pragma unroll
    for (int n = 0; n < 4; n++) {
        int col = c0 + wc * 64 + n * 16 + (lane & 15);
        float bs = bias[col];
#pragma unroll
        for (int m = 0; m < 4; m++) {
#pragma unroll
            for (int r = 0; r < 4; r++) {
                int row = m0 + wr * 64 + m * 16 + ((lane >> 4) << 2) + r;
                dst[(size_t)row * ldd + col] = f2b(acc[m][n][r] + bs);
            }
        }
    }
}

// ---------------- RoPE in-place on q (x 1/8) and k ----------------
__global__ __launch_bounds__(256) void rope_kernel(unsigned short* __restrict__ qb,
                                                   unsigned short* __restrict__ kb) {
    int tid = blockIdx.x * 256 + threadIdx.x;       // 4096*16*32 threads
    int i = tid & 31;
    int head = (tid >> 5) & 15;
    int tok = tid >> 9;
    int pos = tok & 2047;
    // freq_i = 10000^(-i/32) = exp2(-i/32 * log2(10000))
    float freq = exp2f(-(float)i * (13.287712379549449f / 32.0f));
    float ang = (float)pos * freq;
    float sn, cs;
    sincosf(ang, &sn, &cs);
    unsigned short* base;
    float scale;
    if (head < 12) { base = qb + ((size_t)tok * 12 + head) * 64; scale = 0.125f; }
    else           { base = kb + ((size_t)tok * 4 + (head - 12)) * 64; scale = 1.0f; }
    float x1 = b2f(base[i]), x2 = b2f(base[i + 32]);
    base[i]      = f2b((x1 * cs - x2 * sn) * scale);
    base[i + 32] = f2b((x1 * sn + x2 * cs) * scale);
}

// ---------------- Flash attention: grid (S/64, B*NH), 4 waves x 16 q-rows ----------------
__global__ __launch_bounds__(256) void flash_kernel(const unsigned short* __restrict__ qb,
                                                    const unsigned short* __restrict__ kb,
                                                    const unsigned short* __restrict__ vb,
                                                    unsigned short* __restrict__ ob) {
    __shared__ short Ks[64 * 64];
    __shared__ short Vs[64 * 64];   // transposed: [d][kv]
    __shared__ short Ss[4 * 16 * 64];
    const int s0 = blockIdx.x * 64;
    const int bh = blockIdx.y;
    const int b = bh / 12, hh = bh % 12, g = hh / 3;
    const int tid = threadIdx.x, lane = tid & 63, w = tid >> 6;

    const unsigned short* qptr =
        qb + ((size_t)(b * 2048 + s0 + w * 16 + (lane & 15)) * 12 + hh) * 64 + ((lane >> 4) << 3);
    bf16x8 aq[2];
    aq[0] = *(const bf16x8*)qptr;
    aq[1] = *(const bf16x8*)(qptr + 32);

    f32x4 accO[4];
#pragma unroll
    for (int n = 0; n < 4; n++) accO[n] = (f32x4){0.f, 0.f, 0.f, 0.f};
    float mrow[4] = {-INFINITY, -INFINITY, -INFINITY, -INFINITY};
    float lrow[4] = {0.f, 0.f, 0.f, 0.f};

    for (int t0 = 0; t0 < 2048; t0 += 64) {
        // stage K (row-major swizzled) and V (transposed swizzled)
#pragma unroll
        for (int it = 0; it < 2; it++) {
            int idx = tid + it * 256;
            int r = idx >> 3, ch = idx & 7;
            size_t gsrc = ((size_t)(b * 2048 + t0 + r) * 4 + g) * 64 + ch * 8;
            bf16x8 kv8 = *(const bf16x8*)(kb + gsrc);
            *(bf16x8*)((char*)Ks + SWZ(r, ch * 16)) = kv8;
            bf16x8 vv8 = *(const bf16x8*)(vb + gsrc);
#pragma unroll
            for (int u = 0; u < 8; u++)
                *(short*)((char*)Vs + SWZ(ch * 8 + u, r * 2)) = vv8[u];
        }
        __syncthreads();

        // S = Q x K^T  (16 q-rows x 64 kv)
        f32x4 sc[4];
#pragma unroll
        for (int ct = 0; ct < 4; ct++) {
            sc[ct] = (f32x4){0.f, 0.f, 0.f, 0.f};
#pragma unroll
            for (int ks = 0; ks < 2; ks++) {
                bf16x8 bk8 = *(const bf16x8*)((char*)Ks + SWZ(ct * 16 + (lane & 15), (lane >> 4) * 16 + ks * 64));
                sc[ct] = __builtin_amdgcn_mfma_f32_16x16x32_bf16(aq[ks], bk8, sc[ct], 0, 0, 0);
            }
        }

        // online softmax (rows distributed: row = 4*(lane>>4)+r, col = 16*ct + (lane&15))
#pragma unroll
        for (int r = 0; r < 4; r++) {
            float mx = fmaxf(fmaxf(sc[0][r], sc[1][r]), fmaxf(sc[2][r], sc[3][r]));
#pragma unroll
            for (int msk = 1; msk < 16; msk <<= 1) mx = fmaxf(mx, __shfl_xor(mx, msk, 64));
            float mnew = fmaxf(mrow[r], mx);
            float al = __expf(mrow[r] - mnew);
            float ls = 0.f;
#pragma unroll
            for (int ct = 0; ct < 4; ct++) {
                float pp = __expf(sc[ct][r] - mnew);
                sc[ct][r] = pp;
                ls += pp;
            }
#pragma unroll
            for (int msk = 1; msk < 16; msk <<= 1) ls += __shfl_xor(ls, msk, 64);
            lrow[r] = lrow[r] * al + ls;
            mrow[r] = mnew;
#pragma unroll
            for (int n = 0; n < 4; n++) accO[n][r] *= al;
        }

        // write P (bf16) into per-wave LDS region in [q][kv] layout
#pragma unroll
        for (int ct = 0; ct < 4; ct++)
#pragma unroll
            for (int r = 0; r < 4; r++)
                *(short*)((char*)Ss + w * 2048 + SWZ(((lane >> 4) << 2) + r, (ct * 16 + (lane & 15)) * 2)) =
                    (short)f2b(sc[ct][r]);

        // O += P x V
#pragma unroll
        for (int ks = 0; ks < 2; ks++) {
            bf16x8 ap = *(const bf16x8*)((char*)Ss + w * 2048 + SWZ(lane & 15, (lane >> 4) * 16 + ks * 64));
#pragma unroll
            for (int n = 0; n < 4; n++) {
                bf16x8 bv8 = *(const bf16x8*)((char*)Vs + SWZ(n * 16 + (lane & 15), (lane >> 4) * 16 + ks * 64));
                accO[n] = __builtin_amdgcn_mfma_f32_16x16x32_bf16(ap, bv8, accO[n], 0, 0, 0);
            }
        }
        __syncthreads();
    }

    // epilogue: divide by l, store bf16 to attn buffer [token][h*64+d]
#pragma unroll
    for (int n = 0; n < 4; n++) {
#pragma unroll
        for (int r = 0; r < 4; r++) {
            float o = accO[n][r] / lrow[r];
            int srow = s0 + w * 16 + ((lane >> 4) << 2) + r;
            ob[((size_t)(b * 2048 + srow) * 12 + hh) * 64 + n * 16 + (lane & 15)] = f2b(o);
        }
    }
}

// ---------------- Output GEMM: M=4096, N=768, K=768, + bias + residual ----------------
__global__ __launch_bounds__(256) void gemm_out(const unsigned short* __restrict__ A,
                                                const float* __restrict__ Wo,
                                                const float* __restrict__ bo,
                                                const float* __restrict__ resid,
                                                float* __restrict__ out) {
    __shared__ short As[128 * 64];
    __shared__ short Bs[128 * 64];
    const int m0 = blockIdx.x * 128;
    const int n0 = blockIdx.y * 128;
    const int tid = threadIdx.x, lane = tid & 63, w = tid >> 6;
    const int wr = w >> 1, wc = w & 1;
    f32x4 acc[4][4];
#pragma unroll
    for (int m = 0; m < 4; m++)
#pragma unroll
        for (int n = 0; n < 4; n++) acc[m][n] = (f32x4){0.f, 0.f, 0.f, 0.f};

    for (int k0 = 0; k0 < 768; k0 += 64) {
#pragma unroll
        for (int it = 0; it < 4; it++) {
            int idx = tid + it * 256;
            int r = idx >> 3, ch = idx & 7;
            bf16x8 val = *(const bf16x8*)(A + (size_t)(m0 + r) * 768 + k0 + ch * 8);
            *(bf16x8*)((char*)As + SWZ(r, ch * 16)) = val;
        }
        {
            int kk = tid >> 2, cg = (tid & 3) * 32;
            const float* src = Wo + (size_t)(k0 + kk) * 768 + n0 + cg;
#pragma unroll
            for (int jj = 0; jj < 8; jj++) {
                float4 f = *(const float4*)(src + jj * 4);
                int n = cg + jj * 4;
                *(short*)((char*)Bs + SWZ(n + 0, kk * 2)) = (short)f2b(f.x);
                *(short*)((char*)Bs + SWZ(n + 1, kk * 2)) = (short)f2b(f.y);
                *(short*)((char*)Bs + SWZ(n + 2, kk * 2)) = (short)f2b(f.z);
                *(short*)((char*)Bs + SWZ(n + 3, kk * 2)) = (short)f2b(f.w);
            }
        }
        __syncthreads();
#pragma unroll
        for (int ks = 0; ks < 2; ks++) {
            bf16x8 a[4], b[4];
#pragma unroll
            for (int m = 0; m < 4; m++)
                a[m] = *(const bf16x8*)((char*)As + SWZ(wr * 64 + m * 16 + (lane & 15), (lane >> 4) * 16 + ks * 64));
#pragma unroll
            for (int n = 0; n < 4; n++)
                b[n] = *(const bf16x8*)((char*)Bs + SWZ(wc * 64 + n * 16 + (lane & 15), (lane >> 4) * 16 + ks * 64));
#pragma unroll
            for (int m = 0; m < 4; m++)
#pragma unroll
                for (int n = 0; n < 4; n++)
                    acc[m][n] = __builtin_amdgcn_mfma_f32_16x16x32_bf16(a[m], b[n], acc[m][n], 0, 0, 0);
        }
        __syncthreads();
    }
#pragma unroll
    for (int n = 0; n < 4; n++) {
        int col = n0 + wc * 64 + n * 16 + (lane & 15);
        float bs = bo[col];
#pragma unroll
        for (int m = 0; m < 4; m++) {
#pragma unroll
            for (int r = 0; r < 4; r++) {
                int row = m0 + wr * 64 + m * 16 + ((lane >> 4) << 2) + r;
                out[(size_t)row * 768 + col] = acc[m][n][r] + bs + resid[(size_t)row * 768 + col];
            }
        }
    }
}

extern "C" void kernel_launch(void* const* d_in, const int* in_sizes, int n_in,
                              void* d_out, int out_size, void* d_ws, size_t ws_size,
                              hipStream_t stream) {
    const float* hs    = (const float*)d_in[0];
    const float* Wq    = (const float*)d_in[1];
    const float* bq    = (const float*)d_in[2];
    const float* Wk    = (const float*)d_in[3];
    const float* bk    = (const float*)d_in[4];
    const float* Wv    = (const float*)d_in[5];
    const float* bv    = (const float*)d_in[6];
    const float* Wo    = (const float*)d_in[7];
    const float* bo    = (const float*)d_in[8];
    const float* gamma = (const float*)d_in[9];
    const float* beta  = (const float*)d_in[10];
    float* out = (float*)d_out;

    char* p = (char*)d_ws;
    unsigned short* hbuf = (unsigned short*)p; p += (size_t)4096 * 768 * 2;   // 6.3 MB
    unsigned short* qbuf = (unsigned short*)p; p += (size_t)4096 * 768 * 2;   // 6.3 MB
    unsigned short* kbuf = (unsigned short*)p; p += (size_t)4096 * 256 * 2;   // 2.1 MB
    unsigned short* vbuf = (unsigned short*)p; p += (size_t)4096 * 256 * 2;   // 2.1 MB
    unsigned short* obuf = (unsigned short*)p; p += (size_t)4096 * 768 * 2;   // 6.3 MB

    ln_kernel<<<1024, 256, 0, stream>>>(hs, gamma, beta, hbuf);
    gemm_qkv<<<dim3(32, 10), 256, 0, stream>>>(hbuf, Wq, Wk, Wv, bq, bk, bv, qbuf, kbuf, vbuf);
    rope_kernel<<<8192, 256, 0, stream>>>(qbuf, kbuf);
    flash_kernel<<<dim3(32, 24), 256, 0, stream>>>(qbuf, kbuf, vbuf, obuf);
    gemm_out<<<dim3(32, 6), 256, 0, stream>>>(obuf, Wo, bo, hs, out);
}

// Round 2
// 121.768 us; speedup vs baseline: 1.6710x; 1.6710x over previous
//
#include <hip/hip_runtime.h>

typedef short bf16x8 __attribute__((ext_vector_type(8)));
typedef float f32x4 __attribute__((ext_vector_type(4)));

#define SWZ(r, cb) ((((int)(r)) << 7) + (((int)(cb)) ^ ((((int)(r)) & 7) << 4)))

__device__ __forceinline__ unsigned short f2b(float f) {
    unsigned u = __builtin_bit_cast(unsigned, f);
    u = (u + 0x7FFFu + ((u >> 16) & 1u)) >> 16;
    return (unsigned short)u;
}
__device__ __forceinline__ float b2f(unsigned short h) {
    unsigned u = ((unsigned)h) << 16;
    return __builtin_bit_cast(float, u);
}

// ---------------- LayerNorm: one wave per token, H=768 ----------------
__global__ __launch_bounds__(256) void ln_kernel(const float* __restrict__ x,
                                                 const float* __restrict__ gamma,
                                                 const float* __restrict__ beta,
                                                 unsigned short* __restrict__ h) {
    int lane = threadIdx.x & 63, wv = threadIdx.x >> 6;
    int tok = blockIdx.x * 4 + wv;
    const float* xr = x + (size_t)tok * 768;
    float v[12];
#pragma unroll
    for (int c = 0; c < 3; c++) {
        float4 t = *(const float4*)(xr + c * 256 + lane * 4);
        v[c * 4 + 0] = t.x; v[c * 4 + 1] = t.y; v[c * 4 + 2] = t.z; v[c * 4 + 3] = t.w;
    }
    float s = 0.f;
#pragma unroll
    for (int j = 0; j < 12; j++) s += v[j];
#pragma unroll
    for (int m = 1; m < 64; m <<= 1) s += __shfl_xor(s, m, 64);
    float mu = s * (1.0f / 768.0f);
    float s2 = 0.f;
#pragma unroll
    for (int j = 0; j < 12; j++) { float d = v[j] - mu; s2 += d * d; }
#pragma unroll
    for (int m = 1; m < 64; m <<= 1) s2 += __shfl_xor(s2, m, 64);
    float rstd = 1.0f / sqrtf(s2 * (1.0f / 768.0f) + 1e-12f);
    unsigned short* hr = h + (size_t)tok * 768;
#pragma unroll
    for (int c = 0; c < 3; c++) {
        float4 g = *(const float4*)(gamma + c * 256 + lane * 4);
        float4 bt = *(const float4*)(beta + c * 256 + lane * 4);
        ushort4 o;
        o.x = f2b((v[c * 4 + 0] - mu) * rstd * g.x + bt.x);
        o.y = f2b((v[c * 4 + 1] - mu) * rstd * g.y + bt.y);
        o.z = f2b((v[c * 4 + 2] - mu) * rstd * g.z + bt.z);
        o.w = f2b((v[c * 4 + 3] - mu) * rstd * g.w + bt.w);
        *(ushort4*)(hr + c * 256 + lane * 4) = o;
    }
}

// ---------------- Weight transpose+convert: fp32 [K][N] -> bf16 [N][K], K=768 ----------------
__global__ __launch_bounds__(256) void transw_kernel(const float* __restrict__ Wq,
                                                     const float* __restrict__ Wk,
                                                     const float* __restrict__ Wv,
                                                     const float* __restrict__ Wo,
                                                     unsigned short* __restrict__ WqT,
                                                     unsigned short* __restrict__ WkT,
                                                     unsigned short* __restrict__ WvT,
                                                     unsigned short* __restrict__ WoT) {
    __shared__ float tile[64][65];
    const float* W; unsigned short* WT; int N;
    switch (blockIdx.z) {
        case 0:  W = Wq; WT = WqT; N = 768; break;
        case 1:  W = Wk; WT = WkT; N = 256; break;
        case 2:  W = Wv; WT = WvT; N = 256; break;
        default: W = Wo; WT = WoT; N = 768; break;
    }
    int n0 = blockIdx.x * 64, k0 = blockIdx.y * 64;
    if (n0 >= N) return;
    int t = threadIdx.x;
#pragma unroll
    for (int i = 0; i < 4; i++) {
        int kr = (t >> 4) + i * 16, nc = (t & 15) * 4;
        float4 f = *(const float4*)(W + (size_t)(k0 + kr) * N + n0 + nc);
        tile[kr][nc + 0] = f.x; tile[kr][nc + 1] = f.y;
        tile[kr][nc + 2] = f.z; tile[kr][nc + 3] = f.w;
    }
    __syncthreads();
#pragma unroll
    for (int i = 0; i < 2; i++) {
        int nr = (t >> 3) + i * 32, kc = (t & 7) * 8;
        bf16x8 o;
#pragma unroll
        for (int j = 0; j < 8; j++) o[j] = (short)f2b(tile[kc + j][nr]);
        *(bf16x8*)(WT + (size_t)(n0 + nr) * 768 + k0 + kc) = o;
    }
}

// ---------------- V transpose: bf16 [b*2048+s][4g][64d] -> [b*4+g][64d][2048s] ----------------
__global__ __launch_bounds__(256) void transv_kernel(const unsigned short* __restrict__ v,
                                                     unsigned short* __restrict__ vt) {
    __shared__ unsigned short tile[64][72];
    int s0 = blockIdx.x * 64;
    int bg = blockIdx.y, b = bg >> 2, g = bg & 3;
    int t = threadIdx.x;
#pragma unroll
    for (int i = 0; i < 2; i++) {
        int sr = (t >> 3) + i * 32, dc = (t & 7) * 8;
        bf16x8 v8 = *(const bf16x8*)(v + ((size_t)(b * 2048 + s0 + sr) * 4 + g) * 64 + dc);
        *(bf16x8*)(&tile[sr][dc]) = v8;
    }
    __syncthreads();
#pragma unroll
    for (int i = 0; i < 2; i++) {
        int dr = (t >> 3) + i * 32, sc = (t & 7) * 8;
        bf16x8 o;
#pragma unroll
        for (int j = 0; j < 8; j++) o[j] = (short)tile[sc + j][dr];
        *(bf16x8*)(vt + ((size_t)bg * 64 + dr) * 2048 + s0 + sc) = o;
    }
}

// ---------------- QKV GEMM: M=4096, N=1280 (768|256|256), K=768, B pre-transposed bf16 ----------------
__global__ __launch_bounds__(256) void gemm_qkv(const unsigned short* __restrict__ A,
                                                const unsigned short* __restrict__ WqT,
                                                const unsigned short* __restrict__ WkT,
                                                const unsigned short* __restrict__ WvT,
                                                const float* __restrict__ bq,
                                                const float* __restrict__ bk,
                                                const float* __restrict__ bv,
                                                unsigned short* __restrict__ qo,
                                                unsigned short* __restrict__ ko,
                                                unsigned short* __restrict__ vo) {
    __shared__ short As[128 * 64];
    __shared__ short Bs[128 * 64];
    const int m0 = blockIdx.x * 128;
    const int n0 = blockIdx.y * 128;
    const unsigned short* WT; const float* bias; unsigned short* dst; int c0, ldd;
    if (n0 < 768)       { WT = WqT + (size_t)n0 * 768;          bias = bq; dst = qo; c0 = n0;        ldd = 768; }
    else if (n0 < 1024) { WT = WkT + (size_t)(n0 - 768) * 768;  bias = bk; dst = ko; c0 = n0 - 768;  ldd = 256; }
    else                { WT = WvT + (size_t)(n0 - 1024) * 768; bias = bv; dst = vo; c0 = n0 - 1024; ldd = 256; }
    const int tid = threadIdx.x, lane = tid & 63, w = tid >> 6;
    const int wr = w >> 1, wc = w & 1;
    f32x4 acc[4][4];
#pragma unroll
    for (int m = 0; m < 4; m++)
#pragma unroll
        for (int n = 0; n < 4; n++) acc[m][n] = (f32x4){0.f, 0.f, 0.f, 0.f};

    for (int k0 = 0; k0 < 768; k0 += 64) {
#pragma unroll
        for (int it = 0; it < 4; it++) {
            int idx = tid + it * 256;
            int r = idx >> 3, ch = idx & 7;
            bf16x8 av = *(const bf16x8*)(A + (size_t)(m0 + r) * 768 + k0 + ch * 8);
            *(bf16x8*)((char*)As + SWZ(r, ch * 16)) = av;
            bf16x8 bvv = *(const bf16x8*)(WT + (size_t)r * 768 + k0 + ch * 8);
            *(bf16x8*)((char*)Bs + SWZ(r, ch * 16)) = bvv;
        }
        __syncthreads();
#pragma unroll
        for (int ks = 0; ks < 2; ks++) {
            bf16x8 a[4], b[4];
#pragma unroll
            for (int m = 0; m < 4; m++)
                a[m] = *(const bf16x8*)((char*)As + SWZ(wr * 64 + m * 16 + (lane & 15), (lane >> 4) * 16 + ks * 64));
#pragma unroll
            for (int n = 0; n < 4; n++)
                b[n] = *(const bf16x8*)((char*)Bs + SWZ(wc * 64 + n * 16 + (lane & 15), (lane >> 4) * 16 + ks * 64));
#pragma unroll
            for (int m = 0; m < 4; m++)
#pragma unroll
                for (int n = 0; n < 4; n++)
                    acc[m][n] = __builtin_amdgcn_mfma_f32_16x16x32_bf16(a[m], b[n], acc[m][n], 0, 0, 0);
        }
        __syncthreads();
    }
#pragma unroll
    for (int n = 0; n < 4; n++) {
        int col = c0 + wc * 64 + n * 16 + (lane & 15);
        float bs = bias[col];
#pragma unroll
        for (int m = 0; m < 4; m++) {
#pragma unroll
            for (int r = 0; r < 4; r++) {
                int row = m0 + wr * 64 + m * 16 + ((lane >> 4) << 2) + r;
                dst[(size_t)row * ldd + col] = f2b(acc[m][n][r] + bs);
            }
        }
    }
}

// ---------------- RoPE in-place on q (x 1/8) and k ----------------
__global__ __launch_bounds__(256) void rope_kernel(unsigned short* __restrict__ qb,
                                                   unsigned short* __restrict__ kb) {
    int tid = blockIdx.x * 256 + threadIdx.x;       // 4096*16*32 threads
    int i = tid & 31;
    int head = (tid >> 5) & 15;
    int tok = tid >> 9;
    int pos = tok & 2047;
    float freq = exp2f(-(float)i * (13.287712379549449f / 32.0f));
    float ang = (float)pos * freq;
    float sn, cs;
    sincosf(ang, &sn, &cs);
    unsigned short* base;
    float scale;
    if (head < 12) { base = qb + ((size_t)tok * 12 + head) * 64; scale = 0.125f; }
    else           { base = kb + ((size_t)tok * 4 + (head - 12)) * 64; scale = 1.0f; }
    float x1 = b2f(base[i]), x2 = b2f(base[i + 32]);
    base[i]      = f2b((x1 * cs - x2 * sn) * scale);
    base[i + 32] = f2b((x1 * sn + x2 * cs) * scale);
}

// ---------------- Flash attention: swapped QK^T, grid (S/64, B*NH), 4 waves x 16 q-rows ----------------
__global__ __launch_bounds__(256) void flash_kernel(const unsigned short* __restrict__ qb,
                                                    const unsigned short* __restrict__ kb,
                                                    const unsigned short* __restrict__ vt,
                                                    unsigned short* __restrict__ ob) {
    __shared__ short Ks[64 * 64];
    __shared__ short Vs[64 * 64];   // V^T tile: [d][kv], swizzled
    __shared__ short Ss[4 * 16 * 64];
    const int s0 = blockIdx.x * 64;
    const int bh = blockIdx.y;
    const int b = bh / 12, hh = bh % 12, g = hh / 3;
    const int tid = threadIdx.x, lane = tid & 63, w = tid >> 6;
    const int h = lane >> 4, l15 = lane & 15;

    // Q as B-operand: col q = l15's row, k-slice d = ks*32 + 8h + j
    const unsigned short* qptr =
        qb + ((size_t)(b * 2048 + s0 + w * 16 + l15) * 12 + hh) * 64 + h * 8;
    bf16x8 bq[2];
    bq[0] = *(const bf16x8*)qptr;
    bq[1] = *(const bf16x8*)(qptr + 32);

    f32x4 accO[4];
#pragma unroll
    for (int n = 0; n < 4; n++) accO[n] = (f32x4){0.f, 0.f, 0.f, 0.f};
    float m_r = -INFINITY, l_r = 0.f;

    short* ssw = (short*)((char*)Ss + w * 2048);

    for (int t0 = 0; t0 < 2048; t0 += 64) {
        // stage K [kv][d] and V^T [d][kv], both vectorized + swizzled
#pragma unroll
        for (int it = 0; it < 2; it++) {
            int idx = tid + it * 256;
            int r = idx >> 3, ch = idx & 7;
            bf16x8 k8 = *(const bf16x8*)(kb + ((size_t)(b * 2048 + t0 + r) * 4 + g) * 64 + ch * 8);
            *(bf16x8*)((char*)Ks + SWZ(r, ch * 16)) = k8;
            bf16x8 v8 = *(const bf16x8*)(vt + ((size_t)(b * 4 + g) * 64 + r) * 2048 + t0 + ch * 8);
            *(bf16x8*)((char*)Vs + SWZ(r, ch * 16)) = v8;
        }
        __syncthreads();

        // S^T = K x Q^T : sc[ct] holds S^T[kv = ct*16 + 4h + r][q = l15]
        f32x4 sc[4];
#pragma unroll
        for (int ct = 0; ct < 4; ct++) {
            sc[ct] = (f32x4){0.f, 0.f, 0.f, 0.f};
#pragma unroll
            for (int ks = 0; ks < 2; ks++) {
                bf16x8 ak = *(const bf16x8*)((char*)Ks + SWZ(ct * 16 + l15, ks * 64 + h * 16));
                sc[ct] = __builtin_amdgcn_mfma_f32_16x16x32_bf16(ak, bq[ks], sc[ct], 0, 0, 0);
            }
        }

        // online softmax for column q = l15 (16 values in-lane, 4 lane-copies over h)
        float mx = fmaxf(fmaxf(fmaxf(sc[0][0], sc[0][1]), fmaxf(sc[0][2], sc[0][3])),
                         fmaxf(fmaxf(sc[1][0], sc[1][1]), fmaxf(sc[1][2], sc[1][3])));
        mx = fmaxf(mx, fmaxf(fmaxf(fmaxf(sc[2][0], sc[2][1]), fmaxf(sc[2][2], sc[2][3])),
                             fmaxf(fmaxf(sc[3][0], sc[3][1]), fmaxf(sc[3][2], sc[3][3]))));
        mx = fmaxf(mx, __shfl_xor(mx, 16, 64));
        mx = fmaxf(mx, __shfl_xor(mx, 32, 64));
        float mnew = fmaxf(m_r, mx);
        float al = __expf(m_r - mnew);
        float ls = 0.f;
#pragma unroll
        for (int ct = 0; ct < 4; ct++)
#pragma unroll
            for (int r = 0; r < 4; r++) {
                float pp = __expf(sc[ct][r] - mnew);
                sc[ct][r] = pp;
                ls += pp;
            }
        ls += __shfl_xor(ls, 16, 64);
        ls += __shfl_xor(ls, 32, 64);
        l_r = l_r * al + ls;
        m_r = mnew;
        // rescale accO rows q' = 4h + r with al fetched from that column's lane
        float alr[4];
#pragma unroll
        for (int r = 0; r < 4; r++) alr[r] = __shfl(al, 4 * h + r, 64);
#pragma unroll
        for (int n = 0; n < 4; n++)
#pragma unroll
            for (int r = 0; r < 4; r++) accO[n][r] *= alr[r];

        // write P to per-wave LDS: row q = l15, kv = ct*16 + 4h + r (4x ds_write_b64)
#pragma unroll
        for (int ct = 0; ct < 4; ct++) {
            ushort4 pk;
            pk.x = f2b(sc[ct][0]); pk.y = f2b(sc[ct][1]);
            pk.z = f2b(sc[ct][2]); pk.w = f2b(sc[ct][3]);
            *(ushort4*)((char*)ssw + (l15 << 7) + (((ct << 5) + (h << 3)) ^ ((l15 & 7) << 4))) = pk;
        }

        // O += P x V  (A = P rows q, B = V^T tile rows d)
#pragma unroll
        for (int s = 0; s < 2; s++) {
            bf16x8 ap = *(const bf16x8*)((char*)ssw + (l15 << 7) + (((s << 6) + (h << 4)) ^ ((l15 & 7) << 4)));
#pragma unroll
            for (int n = 0; n < 4; n++) {
                bf16x8 bv8 = *(const bf16x8*)((char*)Vs + SWZ(n * 16 + l15, s * 64 + h * 16));
                accO[n] = __builtin_amdgcn_mfma_f32_16x16x32_bf16(ap, bv8, accO[n], 0, 0, 0);
            }
        }
        __syncthreads();
    }

    // epilogue: fetch l for rows q' = 4h + r, divide, store
    float lr[4];
#pragma unroll
    for (int r = 0; r < 4; r++) lr[r] = __shfl(l_r, 4 * h + r, 64);
#pragma unroll
    for (int n = 0; n < 4; n++) {
#pragma unroll
        for (int r = 0; r < 4; r++) {
            float o = accO[n][r] / lr[r];
            int srow = s0 + w * 16 + 4 * h + r;
            ob[((size_t)(b * 2048 + srow) * 12 + hh) * 64 + n * 16 + l15] = f2b(o);
        }
    }
}

// ---------------- Output GEMM: M=4096, N=768, K=768, + bias + residual ----------------
__global__ __launch_bounds__(256) void gemm_out(const unsigned short* __restrict__ A,
                                                const unsigned short* __restrict__ WoT,
                                                const float* __restrict__ bo,
                                                const float* __restrict__ resid,
                                                float* __restrict__ out) {
    __shared__ short As[128 * 64];
    __shared__ short Bs[128 * 64];
    const int m0 = blockIdx.x * 128;
    const int n0 = blockIdx.y * 128;
    const int tid = threadIdx.x, lane = tid & 63, w = tid >> 6;
    const int wr = w >> 1, wc = w & 1;
    f32x4 acc[4][4];
#pragma unroll
    for (int m = 0; m < 4; m++)
#pragma unroll
        for (int n = 0; n < 4; n++) acc[m][n] = (f32x4){0.f, 0.f, 0.f, 0.f};

    for (int k0 = 0; k0 < 768; k0 += 64) {
#pragma unroll
        for (int it = 0; it < 4; it++) {
            int idx = tid + it * 256;
            int r = idx >> 3, ch = idx & 7;
            bf16x8 av = *(const bf16x8*)(A + (size_t)(m0 + r) * 768 + k0 + ch * 8);
            *(bf16x8*)((char*)As + SWZ(r, ch * 16)) = av;
            bf16x8 bvv = *(const bf16x8*)(WoT + (size_t)(n0 + r) * 768 + k0 + ch * 8);
            *(bf16x8*)((char*)Bs + SWZ(r, ch * 16)) = bvv;
        }
        __syncthreads();
#pragma unroll
        for (int ks = 0; ks < 2; ks++) {
            bf16x8 a[4], b[4];
#pragma unroll
            for (int m = 0; m < 4; m++)
                a[m] = *(const bf16x8*)((char*)As + SWZ(wr * 64 + m * 16 + (lane & 15), (lane >> 4) * 16 + ks * 64));
#pragma unroll
            for (int n = 0; n < 4; n++)
                b[n] = *(const bf16x8*)((char*)Bs + SWZ(wc * 64 + n * 16 + (lane & 15), (lane >> 4) * 16 + ks * 64));
#pragma unroll
            for (int m = 0; m < 4; m++)
#pragma unroll
                for (int n = 0; n < 4; n++)
                    acc[m][n] = __builtin_amdgcn_mfma_f32_16x16x32_bf16(a[m], b[n], acc[m][n], 0, 0, 0);
        }
        __syncthreads();
    }
#pragma unroll
    for (int n = 0; n < 4; n++) {
        int col = n0 + wc * 64 + n * 16 + (lane & 15);
        float bs = bo[col];
#pragma unroll
        for (int m = 0; m < 4; m++) {
#pragma unroll
            for (int r = 0; r < 4; r++) {
                int row = m0 + wr * 64 + m * 16 + ((lane >> 4) << 2) + r;
                out[(size_t)row * 768 + col] = acc[m][n][r] + bs + resid[(size_t)row * 768 + col];
            }
        }
    }
}

extern "C" void kernel_launch(void* const* d_in, const int* in_sizes, int n_in,
                              void* d_out, int out_size, void* d_ws, size_t ws_size,
                              hipStream_t stream) {
    const float* hs    = (const float*)d_in[0];
    const float* Wq    = (const float*)d_in[1];
    const float* bq    = (const float*)d_in[2];
    const float* Wk    = (const float*)d_in[3];
    const float* bk    = (const float*)d_in[4];
    const float* Wv    = (const float*)d_in[5];
    const float* bv    = (const float*)d_in[6];
    const float* Wo    = (const float*)d_in[7];
    const float* bo    = (const float*)d_in[8];
    const float* gamma = (const float*)d_in[9];
    const float* beta  = (const float*)d_in[10];
    float* out = (float*)d_out;

    char* p = (char*)d_ws;
    unsigned short* hbuf = (unsigned short*)p; p += (size_t)4096 * 768 * 2;   // LN out; reused as attn out
    unsigned short* qbuf = (unsigned short*)p; p += (size_t)4096 * 768 * 2;
    unsigned short* kbuf = (unsigned short*)p; p += (size_t)4096 * 256 * 2;
    unsigned short* vbuf = (unsigned short*)p; p += (size_t)4096 * 256 * 2;
    unsigned short* vtbuf = (unsigned short*)p; p += (size_t)4096 * 256 * 2;
    unsigned short* WqT = (unsigned short*)p; p += (size_t)768 * 768 * 2;
    unsigned short* WkT = (unsigned short*)p; p += (size_t)256 * 768 * 2;
    unsigned short* WvT = (unsigned short*)p; p += (size_t)256 * 768 * 2;
    unsigned short* WoT = (unsigned short*)p; p += (size_t)768 * 768 * 2;
    unsigned short* obuf = hbuf;   // alias: hbuf dead after gemm_qkv

    ln_kernel<<<1024, 256, 0, stream>>>(hs, gamma, beta, hbuf);
    transw_kernel<<<dim3(12, 12, 4), 256, 0, stream>>>(Wq, Wk, Wv, Wo, WqT, WkT, WvT, WoT);
    gemm_qkv<<<dim3(32, 10), 256, 0, stream>>>(hbuf, WqT, WkT, WvT, bq, bk, bv, qbuf, kbuf, vbuf);
    rope_kernel<<<8192, 256, 0, stream>>>(qbuf, kbuf);
    transv_kernel<<<dim3(32, 8), 256, 0, stream>>>(vbuf, vtbuf);
    flash_kernel<<<dim3(32, 24), 256, 0, stream>>>(qbuf, kbuf, vtbuf, obuf);
    gemm_out<<<dim3(32, 6), 256, 0, stream>>>(obuf, WoT, bo, hs, out);
}

// Round 3
// 99.750 us; speedup vs baseline: 2.0399x; 1.2207x over previous
//
#include <hip/hip_runtime.h>

typedef short bf16x8 __attribute__((ext_vector_type(8)));
typedef float f32x4 __attribute__((ext_vector_type(4)));

#define SWZ(r, cb) ((((int)(r)) << 7) + (((int)(cb)) ^ ((((int)(r)) & 7) << 4)))

__device__ __forceinline__ unsigned short f2b(float f) {
    unsigned u = __builtin_bit_cast(unsigned, f);
    u = (u + 0x7FFFu + ((u >> 16) & 1u)) >> 16;
    return (unsigned short)u;
}
__device__ __forceinline__ float b2f(unsigned short h) {
    unsigned u = ((unsigned)h) << 16;
    return __builtin_bit_cast(float, u);
}
__device__ __forceinline__ void gload16(void* lds, const void* gsrc) {
    __builtin_amdgcn_global_load_lds((const __attribute__((address_space(1))) void*)gsrc,
                                     (__attribute__((address_space(3))) void*)lds, 16, 0, 0);
}

// ---------------- LayerNorm: one wave per token, H=768 ----------------
__global__ __launch_bounds__(256) void ln_kernel(const float* __restrict__ x,
                                                 const float* __restrict__ gamma,
                                                 const float* __restrict__ beta,
                                                 unsigned short* __restrict__ h) {
    int lane = threadIdx.x & 63, wv = threadIdx.x >> 6;
    int tok = blockIdx.x * 4 + wv;
    const float* xr = x + (size_t)tok * 768;
    float v[12];
#pragma unroll
    for (int c = 0; c < 3; c++) {
        float4 t = *(const float4*)(xr + c * 256 + lane * 4);
        v[c * 4 + 0] = t.x; v[c * 4 + 1] = t.y; v[c * 4 + 2] = t.z; v[c * 4 + 3] = t.w;
    }
    float s = 0.f;
#pragma unroll
    for (int j = 0; j < 12; j++) s += v[j];
#pragma unroll
    for (int m = 1; m < 64; m <<= 1) s += __shfl_xor(s, m, 64);
    float mu = s * (1.0f / 768.0f);
    float s2 = 0.f;
#pragma unroll
    for (int j = 0; j < 12; j++) { float d = v[j] - mu; s2 += d * d; }
#pragma unroll
    for (int m = 1; m < 64; m <<= 1) s2 += __shfl_xor(s2, m, 64);
    float rstd = 1.0f / sqrtf(s2 * (1.0f / 768.0f) + 1e-12f);
    unsigned short* hr = h + (size_t)tok * 768;
#pragma unroll
    for (int c = 0; c < 3; c++) {
        float4 g = *(const float4*)(gamma + c * 256 + lane * 4);
        float4 bt = *(const float4*)(beta + c * 256 + lane * 4);
        ushort4 o;
        o.x = f2b((v[c * 4 + 0] - mu) * rstd * g.x + bt.x);
        o.y = f2b((v[c * 4 + 1] - mu) * rstd * g.y + bt.y);
        o.z = f2b((v[c * 4 + 2] - mu) * rstd * g.z + bt.z);
        o.w = f2b((v[c * 4 + 3] - mu) * rstd * g.w + bt.w);
        *(ushort4*)(hr + c * 256 + lane * 4) = o;
    }
}

// ---------------- Weight transpose+convert: fp32 [K][N] -> bf16 [N][K], K=768 ----------------
__global__ __launch_bounds__(256) void transw_kernel(const float* __restrict__ Wq,
                                                     const float* __restrict__ Wk,
                                                     const float* __restrict__ Wv,
                                                     const float* __restrict__ Wo,
                                                     unsigned short* __restrict__ WqT,
                                                     unsigned short* __restrict__ WkT,
                                                     unsigned short* __restrict__ WvT,
                                                     unsigned short* __restrict__ WoT) {
    __shared__ float tile[64][65];
    const float* W; unsigned short* WT; int N;
    switch (blockIdx.z) {
        case 0:  W = Wq; WT = WqT; N = 768; break;
        case 1:  W = Wk; WT = WkT; N = 256; break;
        case 2:  W = Wv; WT = WvT; N = 256; break;
        default: W = Wo; WT = WoT; N = 768; break;
    }
    int n0 = blockIdx.x * 64, k0 = blockIdx.y * 64;
    if (n0 >= N) return;
    int t = threadIdx.x;
#pragma unroll
    for (int i = 0; i < 4; i++) {
        int kr = (t >> 4) + i * 16, nc = (t & 15) * 4;
        float4 f = *(const float4*)(W + (size_t)(k0 + kr) * N + n0 + nc);
        tile[kr][nc + 0] = f.x; tile[kr][nc + 1] = f.y;
        tile[kr][nc + 2] = f.z; tile[kr][nc + 3] = f.w;
    }
    __syncthreads();
#pragma unroll
    for (int i = 0; i < 2; i++) {
        int nr = (t >> 3) + i * 32, kc = (t & 7) * 8;
        bf16x8 o;
#pragma unroll
        for (int j = 0; j < 8; j++) o[j] = (short)f2b(tile[kc + j][nr]);
        *(bf16x8*)(WT + (size_t)(n0 + nr) * 768 + k0 + kc) = o;
    }
}

// ---------------- V transpose: bf16 [b*2048+s][4g][64d] -> [b*4+g][64d][2048s] ----------------
__global__ __launch_bounds__(256) void transv_kernel(const unsigned short* __restrict__ v,
                                                     unsigned short* __restrict__ vt) {
    __shared__ unsigned short tile[64][72];
    int s0 = blockIdx.x * 64;
    int bg = blockIdx.y, b = bg >> 2, g = bg & 3;
    int t = threadIdx.x;
#pragma unroll
    for (int i = 0; i < 2; i++) {
        int sr = (t >> 3) + i * 32, dc = (t & 7) * 8;
        bf16x8 v8 = *(const bf16x8*)(v + ((size_t)(b * 2048 + s0 + sr) * 4 + g) * 64 + dc);
        *(bf16x8*)(&tile[sr][dc]) = v8;
    }
    __syncthreads();
#pragma unroll
    for (int i = 0; i < 2; i++) {
        int dr = (t >> 3) + i * 32, sc = (t & 7) * 8;
        bf16x8 o;
#pragma unroll
        for (int j = 0; j < 8; j++) o[j] = (short)tile[sc + j][dr];
        *(bf16x8*)(vt + ((size_t)bg * 64 + dr) * 2048 + s0 + sc) = o;
    }
}

// ---------------- RoPE in-place on k only (q done in flash) ----------------
__global__ __launch_bounds__(256) void rope_k(unsigned short* __restrict__ kb) {
    int tid = blockIdx.x * 256 + threadIdx.x;   // 4096*4*32 threads
    int i = tid & 31;
    int g = (tid >> 5) & 3;
    int tok = tid >> 7;
    int pos = tok & 2047;
    float freq = exp2f(-(float)i * (13.287712379549449f / 32.0f));
    float ang = (float)pos * freq;
    float sn, cs;
    sincosf(ang, &sn, &cs);
    unsigned short* base = kb + ((size_t)tok * 4 + g) * 64;
    float x1 = b2f(base[i]), x2 = b2f(base[i + 32]);
    base[i]      = f2b(x1 * cs - x2 * sn);
    base[i + 32] = f2b(x1 * sn + x2 * cs);
}

// ---------------- QKV GEMM: 128x128 tile, gload_lds staging, 2-phase dbuf ----------------
__global__ __launch_bounds__(256) void gemm_qkv(const unsigned short* __restrict__ A,
                                                const unsigned short* __restrict__ WqT,
                                                const unsigned short* __restrict__ WkT,
                                                const unsigned short* __restrict__ WvT,
                                                const float* __restrict__ bq,
                                                const float* __restrict__ bk,
                                                const float* __restrict__ bv,
                                                unsigned short* __restrict__ qo,
                                                unsigned short* __restrict__ ko,
                                                unsigned short* __restrict__ vo) {
    __shared__ __align__(1024) char smem[65536];   // A bufs @0,16384; B bufs @32768,49152
    const int m0 = blockIdx.x * 128;
    const int n0 = blockIdx.y * 128;
    const unsigned short* WT; const float* bias; unsigned short* dst; int c0, ldd;
    if (n0 < 768)       { WT = WqT + (size_t)n0 * 768;          bias = bq; dst = qo; c0 = n0;        ldd = 768; }
    else if (n0 < 1024) { WT = WkT + (size_t)(n0 - 768) * 768;  bias = bk; dst = ko; c0 = n0 - 768;  ldd = 256; }
    else                { WT = WvT + (size_t)(n0 - 1024) * 768; bias = bv; dst = vo; c0 = n0 - 1024; ldd = 256; }
    const int tid = threadIdx.x, lane = tid & 63, w = tid >> 6;
    const int wr = w >> 1, wc = w & 1;
    const int rl = lane >> 3, cl = lane & 7;
    const int scol = (cl * 16) ^ (rl << 4);

    const char* srcA0 = (const char*)A  + (size_t)(m0 + w * 32 +  0 + rl) * 1536 + scol;
    const char* srcA1 = (const char*)A  + (size_t)(m0 + w * 32 +  8 + rl) * 1536 + scol;
    const char* srcA2 = (const char*)A  + (size_t)(m0 + w * 32 + 16 + rl) * 1536 + scol;
    const char* srcA3 = (const char*)A  + (size_t)(m0 + w * 32 + 24 + rl) * 1536 + scol;
    const char* srcB0 = (const char*)WT + (size_t)(w * 32 +  0 + rl) * 1536 + scol;
    const char* srcB1 = (const char*)WT + (size_t)(w * 32 +  8 + rl) * 1536 + scol;
    const char* srcB2 = (const char*)WT + (size_t)(w * 32 + 16 + rl) * 1536 + scol;
    const char* srcB3 = (const char*)WT + (size_t)(w * 32 + 24 + rl) * 1536 + scol;
    const int cb = w * 4096;  // chunk base bytes for this wave (4 chunks x 1024)

    f32x4 acc[4][4];
#pragma unroll
    for (int m = 0; m < 4; m++)
#pragma unroll
        for (int n = 0; n < 4; n++) acc[m][n] = (f32x4){0.f, 0.f, 0.f, 0.f};

    // prologue: stage k-step 0 into buf 0
    gload16(smem + cb +    0, srcA0); gload16(smem + cb + 1024, srcA1);
    gload16(smem + cb + 2048, srcA2); gload16(smem + cb + 3072, srcA3);
    gload16(smem + 32768 + cb +    0, srcB0); gload16(smem + 32768 + cb + 1024, srcB1);
    gload16(smem + 32768 + cb + 2048, srcB2); gload16(smem + 32768 + cb + 3072, srcB3);
    __syncthreads();

    for (int t = 0; t < 12; ++t) {
        const int cur = t & 1;
        if (t < 11) {
            srcA0 += 128; srcA1 += 128; srcA2 += 128; srcA3 += 128;
            srcB0 += 128; srcB1 += 128; srcB2 += 128; srcB3 += 128;
            char* ab = smem + (cur ^ 1) * 16384 + cb;
            char* bb = smem + 32768 + (cur ^ 1) * 16384 + cb;
            gload16(ab +    0, srcA0); gload16(ab + 1024, srcA1);
            gload16(ab + 2048, srcA2); gload16(ab + 3072, srcA3);
            gload16(bb +    0, srcB0); gload16(bb + 1024, srcB1);
            gload16(bb + 2048, srcB2); gload16(bb + 3072, srcB3);
        }
        const char* Ab = smem + cur * 16384;
        const char* Bb = smem + 32768 + cur * 16384;
#pragma unroll
        for (int ks = 0; ks < 2; ks++) {
            bf16x8 a[4], b[4];
#pragma unroll
            for (int m = 0; m < 4; m++)
                a[m] = *(const bf16x8*)(Ab + SWZ(wr * 64 + m * 16 + (lane & 15), (lane >> 4) * 16 + ks * 64));
#pragma unroll
            for (int n = 0; n < 4; n++)
                b[n] = *(const bf16x8*)(Bb + SWZ(wc * 64 + n * 16 + (lane & 15), (lane >> 4) * 16 + ks * 64));
#pragma unroll
            for (int m = 0; m < 4; m++)
#pragma unroll
                for (int n = 0; n < 4; n++)
                    acc[m][n] = __builtin_amdgcn_mfma_f32_16x16x32_bf16(a[m], b[n], acc[m][n], 0, 0, 0);
        }
        __syncthreads();
    }
#pragma unroll
    for (int n = 0; n < 4; n++) {
        int col = c0 + wc * 64 + n * 16 + (lane & 15);
        float bs = bias[col];
#pragma unroll
        for (int m = 0; m < 4; m++) {
#pragma unroll
            for (int r = 0; r < 4; r++) {
                int row = m0 + wr * 64 + m * 16 + ((lane >> 4) << 2) + r;
                dst[(size_t)row * ldd + col] = f2b(acc[m][n][r] + bs);
            }
        }
    }
}

// ---------------- Flash attention: 12 waves (3 heads x 4 q-groups), gload_lds dbuf ----------------
__global__ __launch_bounds__(768) void flash_kernel(const unsigned short* __restrict__ qb,
                                                    const unsigned short* __restrict__ kb,
                                                    const unsigned short* __restrict__ vt,
                                                    unsigned short* __restrict__ ob) {
    __shared__ __align__(1024) char smem[57344];  // Ks@0 (2x8K), Vs@16384 (2x8K), Ss@32768 (12x2K)
    const int s0 = blockIdx.x * 64;
    const int bg = blockIdx.y, b = bg >> 2, g = bg & 3;
    const int tid = threadIdx.x, lane = tid & 63, w = tid >> 6;
    const int h = lane >> 4, l15 = lane & 15;
    const int hq = w >> 2, qw = w & 3;
    const int hh = g * 3 + hq;

    // staging assignment: waves 0-7 -> K chunks 0-7; waves 8-11 -> V chunks 0-3; waves 0-3 also V chunks 4-7
    const int rl = lane >> 3, cl = lane & 7;
    const int scol = (cl * 16) ^ (rl << 4);
    const char* gsrc1; int ldsoff1; long stride1;
    if (w < 8) {
        int r = w * 8 + rl;
        gsrc1 = (const char*)kb + (((size_t)(b * 2048 + r) * 4 + g) << 7) + scol;
        stride1 = 32768;            // 64 kv rows x 512B
        ldsoff1 = w * 1024;         // Ks region
    } else {
        int d = (w - 8) * 8 + rl;
        gsrc1 = (const char*)vt + (((size_t)bg * 64 + d) << 12) + scol;
        stride1 = 128;              // +64 s
        ldsoff1 = 16384 + (w - 8) * 1024;  // Vs region
    }
    const char* gsrc2 = nullptr; int ldsoff2 = 0;
    if (w < 4) {
        int d = (w + 4) * 8 + rl;
        gsrc2 = (const char*)vt + (((size_t)bg * 64 + d) << 12) + scol;
        ldsoff2 = 16384 + (w + 4) * 1024;
    }

    // Q: load raw, apply RoPE + scale (1/8 * log2e) in registers, once
    const int pos = s0 + qw * 16 + l15;
    const unsigned short* qptr = qb + ((size_t)(b * 2048 + pos) * 12 + hh) * 64 + h * 8;
    bf16x8 q0 = *(const bf16x8*)qptr;
    bf16x8 q1 = *(const bf16x8*)(qptr + 32);
    bf16x8 bqf[2];
    {
        const float SC = 0.125f * 1.4426950408889634f;
#pragma unroll
        for (int j = 0; j < 8; j++) {
            int i = h * 8 + j;
            float freq = exp2f(-(float)i * (13.287712379549449f / 32.0f));
            float sn, cs;
            sincosf((float)pos * freq, &sn, &cs);
            float x1 = b2f((unsigned short)q0[j]), x2 = b2f((unsigned short)q1[j]);
            bqf[0][j] = (short)f2b((x1 * cs - x2 * sn) * SC);
            bqf[1][j] = (short)f2b((x1 * sn + x2 * cs) * SC);
        }
    }

    f32x4 accO[4];
#pragma unroll
    for (int n = 0; n < 4; n++) accO[n] = (f32x4){0.f, 0.f, 0.f, 0.f};
    float m_r = -1e30f, l_r = 0.f;
    char* ssw = smem + 32768 + w * 2048;
    const int sw = (l15 & 7) << 4;

    // prologue: stage tile 0 into buf 0
    gload16(smem + ldsoff1, gsrc1);
    if (w < 4) gload16(smem + ldsoff2, gsrc2);
    __syncthreads();

    for (int t = 0; t < 32; ++t) {
        const int cur = t & 1;
        if (t < 31) {
            gsrc1 += stride1;
            gload16(smem + (cur ^ 1) * 8192 + ldsoff1, gsrc1);
            if (w < 4) { gsrc2 += 128; gload16(smem + (cur ^ 1) * 8192 + ldsoff2, gsrc2); }
        }
        const char* kbase = smem + cur * 8192;
        const char* vbase = smem + 16384 + cur * 8192;

        // S^T = K x Q^T : sc[ct][r] = S[q=l15][kv=ct*16+4h+r] (log2 domain)
        f32x4 sc[4];
#pragma unroll
        for (int ct = 0; ct < 4; ct++) {
            sc[ct] = (f32x4){0.f, 0.f, 0.f, 0.f};
#pragma unroll
            for (int ks = 0; ks < 2; ks++) {
                bf16x8 ak = *(const bf16x8*)(kbase + ((ct * 16 + l15) << 7) + ((ks * 64 + h * 16) ^ sw));
                sc[ct] = __builtin_amdgcn_mfma_f32_16x16x32_bf16(ak, bqf[ks], sc[ct], 0, 0, 0);
            }
        }

        // online softmax in log2 domain with deferred rescale (THR=8)
        float mx = fmaxf(fmaxf(fmaxf(sc[0][0], sc[0][1]), fmaxf(sc[0][2], sc[0][3])),
                         fmaxf(fmaxf(sc[1][0], sc[1][1]), fmaxf(sc[1][2], sc[1][3])));
        mx = fmaxf(mx, fmaxf(fmaxf(fmaxf(sc[2][0], sc[2][1]), fmaxf(sc[2][2], sc[2][3])),
                             fmaxf(fmaxf(sc[3][0], sc[3][1]), fmaxf(sc[3][2], sc[3][3]))));
        mx = fmaxf(mx, __shfl_xor(mx, 16, 64));
        mx = fmaxf(mx, __shfl_xor(mx, 32, 64));
        if (__any(mx > m_r + 8.0f)) {
            float mnew = fmaxf(m_r, mx);
            float al = __builtin_amdgcn_exp2f(m_r - mnew);
            m_r = mnew;
            float alr[4];
#pragma unroll
            for (int r = 0; r < 4; r++) alr[r] = __shfl(al, 4 * h + r, 64);
#pragma unroll
            for (int n = 0; n < 4; n++)
#pragma unroll
                for (int r = 0; r < 4; r++) accO[n][r] *= alr[r];
            l_r *= al;
        }
        float ls = 0.f;
#pragma unroll
        for (int ct = 0; ct < 4; ct++)
#pragma unroll
            for (int r = 0; r < 4; r++) {
                float p = __builtin_amdgcn_exp2f(sc[ct][r] - m_r);
                sc[ct][r] = p;
                ls += p;
            }
        ls += __shfl_xor(ls, 16, 64);
        ls += __shfl_xor(ls, 32, 64);
        l_r += ls;

        // P -> bf16 via cvt_pk, write to per-wave LDS (row q=l15)
#pragma unroll
        for (int ct = 0; ct < 4; ct++) {
            unsigned plo, phi;
            asm("v_cvt_pk_bf16_f32 %0, %1, %2" : "=v"(plo) : "v"(sc[ct][0]), "v"(sc[ct][1]));
            asm("v_cvt_pk_bf16_f32 %0, %1, %2" : "=v"(phi) : "v"(sc[ct][2]), "v"(sc[ct][3]));
            uint2 pk; pk.x = plo; pk.y = phi;
            *(uint2*)(ssw + (l15 << 7) + ((ct * 32 + h * 8) ^ sw)) = pk;
        }

        // O += P x V
#pragma unroll
        for (int s = 0; s < 2; s++) {
            bf16x8 ap = *(const bf16x8*)(ssw + (l15 << 7) + ((s * 64 + h * 16) ^ sw));
#pragma unroll
            for (int n = 0; n < 4; n++) {
                bf16x8 bv8 = *(const bf16x8*)(vbase + ((n * 16 + l15) << 7) + ((s * 64 + h * 16) ^ sw));
                accO[n] = __builtin_amdgcn_mfma_f32_16x16x32_bf16(ap, bv8, accO[n], 0, 0, 0);
            }
        }
        __syncthreads();
    }

    // epilogue
    float lr[4];
#pragma unroll
    for (int r = 0; r < 4; r++) lr[r] = __builtin_amdgcn_rcpf(__shfl(l_r, 4 * h + r, 64));
#pragma unroll
    for (int n = 0; n < 4; n++) {
#pragma unroll
        for (int r = 0; r < 4; r++) {
            int srow = s0 + qw * 16 + 4 * h + r;
            ob[((size_t)(b * 2048 + srow) * 12 + hh) * 64 + n * 16 + l15] = f2b(accO[n][r] * lr[r]);
        }
    }
}

// ---------------- Output GEMM: 128x128 tile, gload_lds staging, + bias + residual ----------------
__global__ __launch_bounds__(256) void gemm_out(const unsigned short* __restrict__ A,
                                                const unsigned short* __restrict__ WoT,
                                                const float* __restrict__ bo,
                                                const float* __restrict__ resid,
                                                float* __restrict__ out) {
    __shared__ __align__(1024) char smem[65536];
    const int m0 = blockIdx.x * 128;
    const int n0 = blockIdx.y * 128;
    const int tid = threadIdx.x, lane = tid & 63, w = tid >> 6;
    const int wr = w >> 1, wc = w & 1;
    const int rl = lane >> 3, cl = lane & 7;
    const int scol = (cl * 16) ^ (rl << 4);

    const char* srcA0 = (const char*)A + (size_t)(m0 + w * 32 +  0 + rl) * 1536 + scol;
    const char* srcA1 = (const char*)A + (size_t)(m0 + w * 32 +  8 + rl) * 1536 + scol;
    const char* srcA2 = (const char*)A + (size_t)(m0 + w * 32 + 16 + rl) * 1536 + scol;
    const char* srcA3 = (const char*)A + (size_t)(m0 + w * 32 + 24 + rl) * 1536 + scol;
    const char* srcB0 = (const char*)WoT + (size_t)(n0 + w * 32 +  0 + rl) * 1536 + scol;
    const char* srcB1 = (const char*)WoT + (size_t)(n0 + w * 32 +  8 + rl) * 1536 + scol;
    const char* srcB2 = (const char*)WoT + (size_t)(n0 + w * 32 + 16 + rl) * 1536 + scol;
    const char* srcB3 = (const char*)WoT + (size_t)(n0 + w * 32 + 24 + rl) * 1536 + scol;
    const int cb = w * 4096;

    f32x4 acc[4][4];
#pragma unroll
    for (int m = 0; m < 4; m++)
#pragma unroll
        for (int n = 0; n < 4; n++) acc[m][n] = (f32x4){0.f, 0.f, 0.f, 0.f};

    gload16(smem + cb +    0, srcA0); gload16(smem + cb + 1024, srcA1);
    gload16(smem + cb + 2048, srcA2); gload16(smem + cb + 3072, srcA3);
    gload16(smem + 32768 + cb +    0, srcB0); gload16(smem + 32768 + cb + 1024, srcB1);
    gload16(smem + 32768 + cb + 2048, srcB2); gload16(smem + 32768 + cb + 3072, srcB3);
    __syncthreads();

    for (int t = 0; t < 12; ++t) {
        const int cur = t & 1;
        if (t < 11) {
            srcA0 += 128; srcA1 += 128; srcA2 += 128; srcA3 += 128;
            srcB0 += 128; srcB1 += 128; srcB2 += 128; srcB3 += 128;
            char* ab = smem + (cur ^ 1) * 16384 + cb;
            char* bb = smem + 32768 + (cur ^ 1) * 16384 + cb;
            gload16(ab +    0, srcA0); gload16(ab + 1024, srcA1);
            gload16(ab + 2048, srcA2); gload16(ab + 3072, srcA3);
            gload16(bb +    0, srcB0); gload16(bb + 1024, srcB1);
            gload16(bb + 2048, srcB2); gload16(bb + 3072, srcB3);
        }
        const char* Ab = smem + cur * 16384;
        const char* Bb = smem + 32768 + cur * 16384;
#pragma unroll
        for (int ks = 0; ks < 2; ks++) {
            bf16x8 a[4], b[4];
#pragma unroll
            for (int m = 0; m < 4; m++)
                a[m] = *(const bf16x8*)(Ab + SWZ(wr * 64 + m * 16 + (lane & 15), (lane >> 4) * 16 + ks * 64));
#pragma unroll
            for (int n = 0; n < 4; n++)
                b[n] = *(const bf16x8*)(Bb + SWZ(wc * 64 + n * 16 + (lane & 15), (lane >> 4) * 16 + ks * 64));
#pragma unroll
            for (int m = 0; m < 4; m++)
#pragma unroll
                for (int n = 0; n < 4; n++)
                    acc[m][n] = __builtin_amdgcn_mfma_f32_16x16x32_bf16(a[m], b[n], acc[m][n], 0, 0, 0);
        }
        __syncthreads();
    }
#pragma unroll
    for (int n = 0; n < 4; n++) {
        int col = n0 + wc * 64 + n * 16 + (lane & 15);
        float bs = bo[col];
#pragma unroll
        for (int m = 0; m < 4; m++) {
#pragma unroll
            for (int r = 0; r < 4; r++) {
                int row = m0 + wr * 64 + m * 16 + ((lane >> 4) << 2) + r;
                out[(size_t)row * 768 + col] = acc[m][n][r] + bs + resid[(size_t)row * 768 + col];
            }
        }
    }
}

extern "C" void kernel_launch(void* const* d_in, const int* in_sizes, int n_in,
                              void* d_out, int out_size, void* d_ws, size_t ws_size,
                              hipStream_t stream) {
    const float* hs    = (const float*)d_in[0];
    const float* Wq    = (const float*)d_in[1];
    const float* bq    = (const float*)d_in[2];
    const float* Wk    = (const float*)d_in[3];
    const float* bk    = (const float*)d_in[4];
    const float* Wv    = (const float*)d_in[5];
    const float* bv    = (const float*)d_in[6];
    const float* Wo    = (const float*)d_in[7];
    const float* bo    = (const float*)d_in[8];
    const float* gamma = (const float*)d_in[9];
    const float* beta  = (const float*)d_in[10];
    float* out = (float*)d_out;

    char* p = (char*)d_ws;
    unsigned short* hbuf = (unsigned short*)p; p += (size_t)4096 * 768 * 2;   // LN out; reused as attn out
    unsigned short* qbuf = (unsigned short*)p; p += (size_t)4096 * 768 * 2;
    unsigned short* kbuf = (unsigned short*)p; p += (size_t)4096 * 256 * 2;
    unsigned short* vbuf = (unsigned short*)p; p += (size_t)4096 * 256 * 2;
    unsigned short* vtbuf = (unsigned short*)p; p += (size_t)4096 * 256 * 2;
    unsigned short* WqT = (unsigned short*)p; p += (size_t)768 * 768 * 2;
    unsigned short* WkT = (unsigned short*)p; p += (size_t)256 * 768 * 2;
    unsigned short* WvT = (unsigned short*)p; p += (size_t)256 * 768 * 2;
    unsigned short* WoT = (unsigned short*)p; p += (size_t)768 * 768 * 2;
    unsigned short* obuf = hbuf;   // alias: hbuf dead after gemm_qkv

    ln_kernel<<<1024, 256, 0, stream>>>(hs, gamma, beta, hbuf);
    transw_kernel<<<dim3(12, 12, 4), 256, 0, stream>>>(Wq, Wk, Wv, Wo, WqT, WkT, WvT, WoT);
    gemm_qkv<<<dim3(32, 10), 256, 0, stream>>>(hbuf, WqT, WkT, WvT, bq, bk, bv, qbuf, kbuf, vbuf);
    rope_k<<<2048, 256, 0, stream>>>(kbuf);
    transv_kernel<<<dim3(32, 8), 256, 0, stream>>>(vbuf, vtbuf);
    flash_kernel<<<dim3(32, 8), 768, 0, stream>>>(qbuf, kbuf, vtbuf, obuf);
    gemm_out<<<dim3(32, 6), 256, 0, stream>>>(obuf, WoT, bo, hs, out);
}